// Round 16
// baseline (6602.312 us; speedup 1.0000x reference)
//
#include <hip/hip_runtime.h>
#include <math.h>

typedef unsigned short u16;
typedef float f32x4 __attribute__((ext_vector_type(4)));
typedef short s16x8 __attribute__((ext_vector_type(8)));

#define ODIM 5000
#define NROWS 8256   // 129*64

__device__ inline u16 f2bf(float f){
  unsigned u = __float_as_uint(f);
  return (u16)((u + 0x7FFFu + ((u >> 16) & 1u)) >> 16);
}
__device__ inline float bf2f(u16 h){ return __uint_as_float(((unsigned)h) << 16); }
__device__ inline float sigm(float x){ return 1.f/(1.f + expf(-x)); }

// ---------------- A0: zero state ----------------
__global__ void a0_init(float* att2, float* dacc, float* z0f, float* z1f,
                        float* c0, float* c1, float* accum){
  int tid = blockIdx.x*256 + threadIdx.x, n = 64*256;
  for (int i=tid;i<2*64*516;i+=n) att2[i]=0.f;
  for (int i=tid;i<40960;i+=n) dacc[i]=0.f;   // dacc[2][64][320] f32
  for (int i=tid;i<32768;i+=n){ z0f[i]=0.f; z1f[i]=0.f; c0[i]=0.f; c1[i]=0.f; }
  if (tid < 8) accum[tid]=0.f;
}

// ---------------- A1: weight convert / pack ----------------
__global__ void a1_wcvt(const float* waenc, const float* wadec,
  const float* wih0, const float* whh0, const float* wih1, const float* whh1,
  const float* bih0, const float* bhh0, const float* bih1, const float* bhh1,
  const float* wout,
  u16* waencT, u16* wdKC, u16* wcat0, u16* wcat1, u16* wee, u16* woutb,
  float* bc0, float* bc1)
{
  int tid = blockIdx.x*blockDim.x + threadIdx.x;
  int nth = gridDim.x*blockDim.x;
  for (int i=tid; i<320*512; i+=nth){
    int n=i>>9, k=i&511;
    waencT[i] = f2bf(waenc[k*320+n]);
    wdKC[i]   = f2bf(wadec[i]);        // [512][320] row-major direct cast
  }
  for (int i=tid; i<2048*1024; i+=nth){
    int np=i>>10, k=i&1023;
    int u=np>>2, g=np&3, r=g*512+u;
    wcat0[i] = f2bf(k<512 ? wih0[r*1024+512+k] : whh0[r*512+(k-512)]);
    wcat1[i] = f2bf(k<512 ? wih1[r*512+k]      : whh1[r*512+(k-512)]);
  }
  for (int i=tid; i<2048*512; i+=nth){
    int np=i>>9, k=i&511;
    int u=np>>2, g=np&3, r=g*512+u;
    wee[i] = f2bf(wih0[r*1024+k]);
  }
  for (int i=tid; i<5000*512; i+=nth) woutb[i] = f2bf(wout[i]);
  for (int i=tid; i<2048; i+=nth){
    int u=i>>2, g=i&3, r=g*512+u;
    bc0[i] = bih0[r]+bhh0[r];
    bc1[i] = bih1[r]+bhh1[r];
  }
}

// ---------------- A2: hm (masked bf16) + enc_pre = tanh(hm @ Wa_enc) ----------------
__global__ __launch_bounds__(256) void a2_encpre(
  const float* __restrict__ hpad, const int* __restrict__ hlen,
  const u16* __restrict__ waencT, u16* __restrict__ hm, u16* __restrict__ encp)
{
  __shared__ u16 A[64][40];
  __shared__ u16 BT[320][40];
  int tid = threadIdx.x, blk = blockIdx.x;
  int wave = tid>>6, lane = tid&63;
  f32x4 acc[20];
  #pragma unroll
  for (int f=0;f<20;f++) acc[f] = (f32x4){0.f,0.f,0.f,0.f};
  int srow = tid>>2, skoff = (tid&3)*8;
  int grow_s = blk*64 + srow;
  int b_s = grow_s/800, t_s = grow_s - b_s*800;
  bool valid_s = t_s < hlen[b_s];
  for (int c=0;c<16;c++){
    int k0 = c*32;
    {
      const float* src = hpad + (size_t)grow_s*512 + k0 + skoff;
      float4 v0 = *(const float4*)(src);
      float4 v1 = *(const float4*)(src+4);
      if (!valid_s){ v0 = make_float4(0,0,0,0); v1 = make_float4(0,0,0,0); }
      short4 p0 = make_short4((short)f2bf(v0.x),(short)f2bf(v0.y),(short)f2bf(v0.z),(short)f2bf(v0.w));
      short4 p1 = make_short4((short)f2bf(v1.x),(short)f2bf(v1.y),(short)f2bf(v1.z),(short)f2bf(v1.w));
      *(short4*)&A[srow][skoff]   = p0;
      *(short4*)&A[srow][skoff+4] = p1;
      *(short4*)(hm + (size_t)grow_s*512 + k0 + skoff)     = p0;
      *(short4*)(hm + (size_t)grow_s*512 + k0 + skoff + 4) = p1;
    }
    for (int id=tid; id<1280; id+=256){
      int n = id>>2, kv = (id&3)*8;
      *(s16x8*)&BT[n][kv] = *(const s16x8*)(waencT + n*512 + k0 + kv);
    }
    __syncthreads();
    s16x8 av = *(const s16x8*)&A[wave*16 + (lane&15)][(lane>>4)*8];
    #pragma unroll
    for (int f=0;f<20;f++){
      s16x8 bv = *(const s16x8*)&BT[f*16+(lane&15)][(lane>>4)*8];
      acc[f] = __builtin_amdgcn_mfma_f32_16x16x32_bf16(av,bv,acc[f],0,0,0);
    }
    __syncthreads();
  }
  #pragma unroll
  for (int f=0;f<20;f++){
    int col = f*16 + (lane&15);
    #pragma unroll
    for (int r=0;r<4;r++){
      int grow = blk*64 + wave*16 + (lane>>4)*4 + r;
      encp[(size_t)grow*320 + col] = f2bf(tanhf(acc[f][r]));
    }
  }
}

// ---------------- A3: geys = embed[ys_in] @ Wee^T + bc0 ----------------
__global__ __launch_bounds__(256) void a3_geys(
  const int* __restrict__ ys, const float* __restrict__ embed,
  const u16* __restrict__ wee, const float* __restrict__ bc0,
  u16* __restrict__ geys)
{
  __shared__ u16 A[64][88];
  __shared__ u16 BT[256][88];
  int t = blockIdx.x, nt = blockIdx.y, tid = threadIdx.x;
  int wave=tid>>6, lane=tid&63;
  f32x4 acc[16];
  #pragma unroll
  for (int f=0;f<16;f++) acc[f]=(f32x4){0.f,0.f,0.f,0.f};
  int srow = tid>>2, skoff=(tid&3)*16;
  int idx = (t==0) ? (ODIM-1) : ys[srow*128 + (t-1)];
  const float* asrc = embed + (size_t)idx*512;
  for (int c=0;c<8;c++){
    int k0=c*64;
    #pragma unroll
    for (int i=0;i<16;i+=4){
      float4 v = *(const float4*)(asrc + k0 + skoff + i);
      *(short4*)&A[srow][skoff+i] =
        make_short4((short)f2bf(v.x),(short)f2bf(v.y),(short)f2bf(v.z),(short)f2bf(v.w));
    }
    for (int id=tid; id<2048; id+=256){
      int n = id>>3, kv=(id&7)*8;
      *(s16x8*)&BT[n][kv] = *(const s16x8*)(wee + (size_t)(nt*256+n)*512 + k0 + kv);
    }
    __syncthreads();
    #pragma unroll
    for (int kk=0;kk<64;kk+=32){
      s16x8 av = *(const s16x8*)&A[wave*16+(lane&15)][kk+(lane>>4)*8];
      #pragma unroll
      for (int f=0;f<16;f++){
        s16x8 bv = *(const s16x8*)&BT[f*16+(lane&15)][kk+(lane>>4)*8];
        acc[f] = __builtin_amdgcn_mfma_f32_16x16x32_bf16(av,bv,acc[f],0,0,0);
      }
    }
    __syncthreads();
  }
  #pragma unroll
  for (int f=0;f<16;f++){
    int colL = f*16+(lane&15);
    int gc = nt*256+colL;
    float bb = bc0[gc];
    #pragma unroll
    for (int r=0;r<4;r++){
      int row = wave*16 + (lane>>4)*4 + r;
      geys[(size_t)(t*64+row)*2048 + gc] = f2bf(acc[f][r] + bb);
    }
  }
}

// ---------------- K1': att(t) [blocks 0..2047] | cell1(t-1) [blocks 2048..2111] ----------------
// att: d = tanh(dacc[p2][b]) read directly (no pd staging); 32 chunks x 25 frames per batch.
// Also zeroes dacc[p2^1] (accumulated next by k2p(t)).
__global__ __launch_bounds__(256) void k1p(
  int t,
  const u16* __restrict__ encp, const u16* __restrict__ hm, const int* __restrict__ hlen,
  float* __restrict__ dacc,
  const u16* __restrict__ wcat1, const float* __restrict__ bc1,
  const u16* __restrict__ z0b, u16* __restrict__ z1b, float* __restrict__ c1,
  u16* __restrict__ zall, float* __restrict__ att)
{
  __shared__ __align__(16) char smem[17408];
  const int blk = blockIdx.x, tid = threadIdx.x;
  const int wave = tid>>6, lane = tid&63;
  const int p2 = (t+1)&1;

  if (blk < 2048){
    int b = blk>>5, ch = blk&31;
    float* attp = att + ((t&1)*64*516);
    float* attl = (float*)smem;          // [4][512]
    float* sl   = (float*)(smem+8192);   // [4]
    float* dl   = (float*)(smem+8224);   // [320]
    // zero other-parity dacc (written next by k2p(t))
    { int gid = blk*256 + tid;
      if (gid < 20480) dacc[(p2^1)*20480 + gid] = 0.f; }
    // d = tanh(dacc[p2][b])
    if (tid < 320) dl[tid] = tanhf(dacc[p2*20480 + b*320 + tid]);
    __syncthreads();
    float dreg[8];
    #pragma unroll
    for (int j=0;j<8;j++) dreg[j] = (lane<40) ? dl[lane*8+j] : 0.f;
    float attacc[8];
    #pragma unroll
    for (int j=0;j<8;j++) attacc[j]=0.f;
    float sacc = 0.f;
    int len = hlen[b];
    int t0 = ch*25;
    int tend = t0+25 < len ? t0+25 : len;
    for (int i0 = t0 + wave; i0 < tend; i0 += 16){
      s16x8 ev[4], hv[4];
      #pragma unroll
      for (int q=0;q<4;q++){
        int tt = i0 + 4*q;
        if (tt < tend){
          if (lane<40) ev[q] = *(const s16x8*)(encp + (size_t)(b*800+tt)*320 + lane*8);
          hv[q] = *(const s16x8*)(hm + (size_t)(b*800+tt)*512 + lane*8);
        }
      }
      #pragma unroll
      for (int q=0;q<4;q++){
        int tt = i0 + 4*q;
        if (tt < tend){
          float e = 0.f;
          if (lane<40){
            #pragma unroll
            for (int j=0;j<8;j++) e += dreg[j]*bf2f((u16)ev[q][j]);
          }
          #pragma unroll
          for (int off=32; off; off>>=1) e += __shfl_xor(e, off);
          float pw = expf(fminf(e, 60.f));
          sacc += pw;
          #pragma unroll
          for (int j=0;j<8;j++) attacc[j] += pw*bf2f((u16)hv[q][j]);
        }
      }
    }
    __syncthreads();
    #pragma unroll
    for (int j=0;j<8;j++) attl[wave*512 + lane*8+j] = attacc[j];
    if (lane==0) sl[wave] = sacc;
    __syncthreads();
    for (int c2 = tid; c2 < 512; c2 += 256){
      float v = attl[c2]+attl[512+c2]+attl[1024+c2]+attl[1536+c2];
      atomicAdd(&attp[b*516 + c2], v);
    }
    if (tid==0) atomicAdd(&attp[b*516 + 512], sl[0]+sl[1]+sl[2]+sl[3]);
  } else {
    // cell1 for step t-1
    if (t < 1) return;
    int nb = blk - 2048;
    const u16* z0n = z0b + p2*64*512;          // z0 of step t-1 (parity (t-1)&1 = p2)
    const u16* z1p = z1b + ((p2^1)*64*512);
    u16* z1n = z1b + p2*64*512;
    u16* zallt = zall + (size_t)(t-1)*64*512;
    u16 (*A)[88]  = (u16(*)[88])smem;
    u16 (*BT)[88] = (u16(*)[88])(smem+11264);
    f32x4 acc[2];
    acc[0]=(f32x4){0.f,0.f,0.f,0.f}; acc[1]=(f32x4){0.f,0.f,0.f,0.f};
    int srow=tid>>2, skoff=(tid&3)*16;
    int brow=tid>>3, bkoff=(tid&7)*8;
    for (int c=0;c<16;c++){
      int k0=c*64;
      const u16* asrc = (c<8) ? (z0n + srow*512 + k0 + skoff)
                              : (z1p + srow*512 + (k0-512) + skoff);
      *(s16x8*)&A[srow][skoff]   = *(const s16x8*)asrc;
      *(s16x8*)&A[srow][skoff+8] = *(const s16x8*)(asrc+8);
      *(s16x8*)&BT[brow][bkoff] = *(const s16x8*)(wcat1 + (size_t)(nb*32+brow)*1024 + k0 + bkoff);
      __syncthreads();
      #pragma unroll
      for (int kk=0;kk<64;kk+=32){
        s16x8 av = *(const s16x8*)&A[wave*16+(lane&15)][kk+(lane>>4)*8];
        #pragma unroll
        for (int f=0;f<2;f++){
          s16x8 bv = *(const s16x8*)&BT[f*16+(lane&15)][kk+(lane>>4)*8];
          acc[f] = __builtin_amdgcn_mfma_f32_16x16x32_bf16(av,bv,acc[f],0,0,0);
        }
      }
      __syncthreads();
    }
    float (*gl)[36] = (float(*)[36])smem;
    #pragma unroll
    for (int f=0;f<2;f++){
      int colL = f*16+(lane&15);
      float bb = bc1[nb*32+colL];
      #pragma unroll
      for (int r=0;r<4;r++){
        int rowL = wave*16+(lane>>4)*4+r;
        gl[rowL][colL] = acc[f][r] + bb;
      }
    }
    __syncthreads();
    for (int it=tid; it<512; it+=256){
      int bb=it>>3, ul=it&7;
      float gi=gl[bb][ul*4], gf=gl[bb][ul*4+1], gg=gl[bb][ul*4+2], go=gl[bb][ul*4+3];
      int ug = nb*8+ul;
      float cp = c1[bb*512+ug];
      float cn = sigm(gf)*cp + sigm(gi)*tanhf(gg);
      float z = sigm(go)*tanhf(cn);
      c1[bb*512+ug]=cn;
      u16 zb = f2bf(z);
      z1n[bb*512+ug]=zb;
      zallt[bb*512+ug]=zb;
    }
  }
}

// ---------------- K2': cell0(t) (64 blocks) + f32 atomic d-partials + att-zero ----------------
__global__ __launch_bounds__(256) void k2p(
  const float* __restrict__ attp, float* __restrict__ attz,
  const u16* __restrict__ z0p, u16* __restrict__ z0n,
  float* __restrict__ c0,
  const u16* __restrict__ wcat0, const u16* __restrict__ geyt,
  const u16* __restrict__ wdKC, float* __restrict__ dacc)
{
  __shared__ __align__(16) char smem[16896];
  __shared__ float sinv[64];
  __shared__ float zsl[512];     // z[b=64][ul=8] for this block's u-slice
  __shared__ u16 wsl[2560];      // wdKC rows nb*8..nb*8+8 (8x320)
  u16 (*A)[88]  = (u16(*)[88])smem;
  u16 (*BT)[88] = (u16(*)[88])(smem+11264);
  int tid = threadIdx.x, nb = blockIdx.x;
  int wave=tid>>6, lane=tid&63;
  if (tid < 64) sinv[tid] = 1.f/attp[tid*516+512];
  for (int id=tid; id<320; id+=256)
    *(s16x8*)&wsl[id*8] = *(const s16x8*)(wdKC + (size_t)nb*2560 + id*8);
  __syncthreads();
  f32x4 acc[2];
  acc[0]=(f32x4){0.f,0.f,0.f,0.f}; acc[1]=(f32x4){0.f,0.f,0.f,0.f};
  int srow=tid>>2, skoff=(tid&3)*16;
  int brow=tid>>3, bkoff=(tid&7)*8;
  for (int c=0;c<16;c++){
    int k0=c*64;
    if (c<8){
      const float* src = attp + srow*516 + k0 + skoff;
      float sv = sinv[srow];
      #pragma unroll
      for (int i=0;i<16;i+=4){
        float4 v = *(const float4*)(src+i);
        *(short4*)&A[srow][skoff+i] = make_short4(
          (short)f2bf(v.x*sv),(short)f2bf(v.y*sv),(short)f2bf(v.z*sv),(short)f2bf(v.w*sv));
      }
    } else {
      const u16* src = z0p + srow*512 + (k0-512) + skoff;
      *(s16x8*)&A[srow][skoff]   = *(const s16x8*)(src);
      *(s16x8*)&A[srow][skoff+8] = *(const s16x8*)(src+8);
    }
    *(s16x8*)&BT[brow][bkoff] = *(const s16x8*)(wcat0 + (size_t)(nb*32+brow)*1024 + k0 + bkoff);
    __syncthreads();
    #pragma unroll
    for (int kk=0;kk<64;kk+=32){
      s16x8 av = *(const s16x8*)&A[wave*16+(lane&15)][kk+(lane>>4)*8];
      #pragma unroll
      for (int f=0;f<2;f++){
        s16x8 bv = *(const s16x8*)&BT[f*16+(lane&15)][kk+(lane>>4)*8];
        acc[f] = __builtin_amdgcn_mfma_f32_16x16x32_bf16(av,bv,acc[f],0,0,0);
      }
    }
    __syncthreads();
  }
  float (*gl)[36] = (float(*)[36])smem;
  #pragma unroll
  for (int f=0;f<2;f++){
    int colL = f*16+(lane&15);
    #pragma unroll
    for (int r=0;r<4;r++){
      int rowL = wave*16+(lane>>4)*4+r;
      gl[rowL][colL] = acc[f][r] + bf2f(geyt[rowL*2048 + nb*32 + colL]);
    }
  }
  __syncthreads();
  for (int it=tid; it<512; it+=256){
    int bb=it>>3, ul=it&7;
    float gi=gl[bb][ul*4], gf=gl[bb][ul*4+1], gg=gl[bb][ul*4+2], go=gl[bb][ul*4+3];
    int ug = nb*8+ul;
    float cp = c0[bb*512+ug];
    float cn = sigm(gf)*cp + sigm(gi)*tanhf(gg);
    float z = sigm(go)*tanhf(cn);
    c0[bb*512+ug]=cn;
    z0n[bb*512+ug]=f2bf(z);
    zsl[it] = z;
  }
  __syncthreads();
  // d-projection partial: atomic f32 accumulate into dacc[b*320+col]
  for (int idx=tid; idx<20480; idx+=256){
    int b = idx/320, col = idx - b*320;
    float a = 0.f;
    #pragma unroll
    for (int ul=0; ul<8; ul++)
      a += zsl[b*8+ul]*bf2f(wsl[ul*320+col]);
    atomicAdd(&dacc[idx], a);
  }
  for (int i=tid + nb*256; i < 64*516; i += 64*256) attz[i] = 0.f;
}

// ---------------- KF: final cell1(128) (64 blocks) ----------------
__global__ __launch_bounds__(256) void kf_cell1(
  const u16* __restrict__ z0n, const u16* __restrict__ z1p,
  u16* __restrict__ z1n, float* __restrict__ c1,
  const u16* __restrict__ wcat1, const float* __restrict__ bc1,
  u16* __restrict__ zallt)
{
  __shared__ __align__(16) char smem[25600];
  int tid = threadIdx.x, wave=tid>>6, lane=tid&63;
  int nb = blockIdx.x;
  u16 (*A)[88]  = (u16(*)[88])smem;
  u16 (*BT)[88] = (u16(*)[88])(smem+11264);
  f32x4 acc[2];
  acc[0]=(f32x4){0.f,0.f,0.f,0.f}; acc[1]=(f32x4){0.f,0.f,0.f,0.f};
  int srow=tid>>2, skoff=(tid&3)*16;
  int brow=tid>>3, bkoff=(tid&7)*8;
  for (int c=0;c<16;c++){
    int k0=c*64;
    const u16* asrc = (c<8) ? (z0n + srow*512 + k0 + skoff)
                            : (z1p + srow*512 + (k0-512) + skoff);
    *(s16x8*)&A[srow][skoff]   = *(const s16x8*)asrc;
    *(s16x8*)&A[srow][skoff+8] = *(const s16x8*)(asrc+8);
    *(s16x8*)&BT[brow][bkoff] = *(const s16x8*)(wcat1 + (size_t)(nb*32+brow)*1024 + k0 + bkoff);
    __syncthreads();
    #pragma unroll
    for (int kk=0;kk<64;kk+=32){
      s16x8 av = *(const s16x8*)&A[wave*16+(lane&15)][kk+(lane>>4)*8];
      #pragma unroll
      for (int f=0;f<2;f++){
        s16x8 bv = *(const s16x8*)&BT[f*16+(lane&15)][kk+(lane>>4)*8];
        acc[f] = __builtin_amdgcn_mfma_f32_16x16x32_bf16(av,bv,acc[f],0,0,0);
      }
    }
    __syncthreads();
  }
  float (*gl)[36] = (float(*)[36])smem;
  #pragma unroll
  for (int f=0;f<2;f++){
    int colL = f*16+(lane&15);
    float bb = bc1[nb*32+colL];
    #pragma unroll
    for (int r=0;r<4;r++){
      int rowL = wave*16+(lane>>4)*4+r;
      gl[rowL][colL] = acc[f][r] + bb;
    }
  }
  __syncthreads();
  for (int it=tid; it<512; it+=256){
    int bb=it>>3, ul=it&7;
    float gi=gl[bb][ul*4], gf=gl[bb][ul*4+1], gg=gl[bb][ul*4+2], go=gl[bb][ul*4+3];
    int ug = nb*8+ul;
    float cp = c1[bb*512+ug];
    float cn = sigm(gf)*cp + sigm(gi)*tanhf(gg);
    float z = sigm(go)*tanhf(cn);
    c1[bb*512+ug]=cn;
    u16 zb = f2bf(z);
    z1n[bb*512+ug]=zb;
    zallt[bb*512+ug]=zb;
  }
}

// ---------------- K4: logits GEMM + per-(row,vtile) softmax partials ----------------
__global__ __launch_bounds__(512) void k4_logits(
  const u16* __restrict__ zall, const u16* __restrict__ woutb,
  const float* __restrict__ b_out, const int* __restrict__ ys,
  float* __restrict__ partials)
{
  __shared__ char smem[46080];
  u16 (*A)[40]  = (u16(*)[40])smem;
  u16 (*BT)[40] = (u16(*)[40])(smem + 5120);
  int t = blockIdx.x, v = blockIdx.y;
  int tid = threadIdx.x, wave = tid>>6, lane = tid&63;
  int mf = wave>>1;
  int nh = (wave&1)*256;
  f32x4 acc[16];
  #pragma unroll
  for (int f=0;f<16;f++) acc[f]=(f32x4){0.f,0.f,0.f,0.f};
  for (int c=0;c<16;c++){
    int k0 = c*32;
    { int row = tid>>3, koff=(tid&7)*4;
      *(short4*)&A[row][koff] = *(const short4*)(zall + (size_t)(t*64+row)*512 + k0 + koff); }
    { int n = v*512 + tid;
      if (n < ODIM){
        const u16* src = woutb + (size_t)n*512 + k0;
        #pragma unroll
        for (int i=0;i<32;i+=8) *(s16x8*)&BT[tid][i] = *(const s16x8*)(src+i);
      } else {
        s16x8 z = 0;
        #pragma unroll
        for (int i=0;i<32;i+=8) *(s16x8*)&BT[tid][i] = z;
      }
    }
    __syncthreads();
    s16x8 av = *(const s16x8*)&A[mf*16 + (lane&15)][(lane>>4)*8];
    #pragma unroll
    for (int f=0;f<16;f++){
      s16x8 bv = *(const s16x8*)&BT[nh + f*16 + (lane&15)][(lane>>4)*8];
      acc[f] = __builtin_amdgcn_mfma_f32_16x16x32_bf16(av,bv,acc[f],0,0,0);
    }
    __syncthreads();
  }
  float (*ll)[518] = (float(*)[518])smem;
  for (int g=0; g<4; g++){
    if (mf == g){
      #pragma unroll
      for (int f=0;f<16;f++){
        int colL = nh + f*16 + (lane&15);
        int gcol = v*512 + colL;
        float bo = (gcol < ODIM) ? b_out[gcol] : 0.f;
        #pragma unroll
        for (int r=0;r<4;r++){
          int rowL = (lane>>4)*4 + r;
          ll[rowL][colL] = acc[f][r] + bo;
        }
      }
    }
    __syncthreads();
    int r = tid>>5, j = tid&31;
    float m = -1e30f, s = 0.f, amax = -1e30f; int aidx = 0;
    #pragma unroll
    for (int i=0;i<16;i++){
      int cL = j + 32*i;
      int gc = v*512 + cL;
      if (gc < ODIM){
        float val = ll[r][cL];
        if (val > m){ s = s*expf(m-val) + 1.f; m = val; }
        else s += expf(val - m);
        if (val > amax){ amax = val; aidx = gc; }
      }
    }
    #pragma unroll
    for (int off=16; off; off>>=1){
      float mo = __shfl_xor(m, off), so = __shfl_xor(s, off);
      float ao = __shfl_xor(amax, off); int io = __shfl_xor(aidx, off);
      float M = fmaxf(m, mo);
      s = s*expf(m-M) + so*expf(mo-M);
      m = M;
      if (ao > amax || (ao == amax && io < aidx)){ amax = ao; aidx = io; }
    }
    if (j == 0){
      int b = g*16 + r;
      int grow = t*64 + b;
      int lab = (t < 128) ? ys[b*128 + t] : (ODIM-1);
      float labval = 0.f, labf = 0.f;
      int lo = lab - v*512;
      if (lo >= 0 && lo < 512){ labval = ll[r][lo]; labf = 1.f; }
      float* pp = partials + (size_t)(grow*10 + v)*8;
      pp[0]=m; pp[1]=s; pp[2]=amax; pp[3]=__int_as_float(aidx); pp[4]=labval; pp[5]=labf;
    }
    __syncthreads();
  }
}

// ---------------- K5: combine partials -> nll/correct -> atomics ----------------
__global__ __launch_bounds__(256) void k5_loss(
  const float* __restrict__ partials, const int* __restrict__ ys, float* accum)
{
  int row = blockIdx.x*256 + threadIdx.x;
  float nll = 0.f; int corr = 0;
  if (row < NROWS){
    float M=-1e30f, S=0.f, amax=-1e30f, labval=0.f; int aidx=0;
    for (int v=0;v<10;v++){
      const float* pp = partials + (size_t)(row*10+v)*8;
      float m=pp[0], s=pp[1], a=pp[2]; int ai=__float_as_int(pp[3]);
      float MM = fmaxf(M, m);
      S = S*expf(M-MM) + s*expf(m-MM);
      M = MM;
      if (a > amax || (a == amax && ai < aidx)){ amax=a; aidx=ai; }
      if (pp[5] != 0.f) labval = pp[4];
    }
    nll = M + logf(S) - labval;
    int t = row>>6, b = row&63;
    int lab = (t < 128) ? ys[b*128+t] : (ODIM-1);
    corr = (aidx == lab) ? 1 : 0;
  }
  __shared__ float sn[256]; __shared__ int sc[256];
  sn[threadIdx.x]=nll; sc[threadIdx.x]=corr; __syncthreads();
  for (int st=128; st; st>>=1){
    if (threadIdx.x<st){ sn[threadIdx.x]+=sn[threadIdx.x+st]; sc[threadIdx.x]+=sc[threadIdx.x+st]; }
    __syncthreads();
  }
  if (threadIdx.x==0){
    atomicAdd(accum, sn[0]);
    atomicAdd((int*)accum + 1, sc[0]);
  }
}

__global__ void k6_final(const float* accum, float* out){
  out[0] = accum[0]/(float)NROWS * 128.f;
  out[1] = (float)(((const int*)accum)[1])/(float)NROWS;
}

// ---------------- launch ----------------
extern "C" void kernel_launch(void* const* d_in, const int* in_sizes, int n_in,
                              void* d_out, int out_size, void* d_ws, size_t ws_size,
                              hipStream_t stream)
{
  const float* hpad  = (const float*)d_in[0];
  const int*   hlen  = (const int*)d_in[1];
  const int*   ys    = (const int*)d_in[2];
  const float* embed = (const float*)d_in[3];
  const float* wih0  = (const float*)d_in[4];
  const float* whh0  = (const float*)d_in[5];
  const float* bih0  = (const float*)d_in[6];
  const float* bhh0  = (const float*)d_in[7];
  const float* wih1  = (const float*)d_in[8];
  const float* whh1  = (const float*)d_in[9];
  const float* bih1  = (const float*)d_in[10];
  const float* bhh1  = (const float*)d_in[11];
  const float* waenc = (const float*)d_in[12];
  const float* wadec = (const float*)d_in[13];
  const float* wout  = (const float*)d_in[14];
  const float* bout  = (const float*)d_in[15];

  char* ws = (char*)d_ws;
  u16*   hm      = (u16*)(ws + 0);              // 52,428,800
  u16*   encp    = (u16*)(ws + 52428800);       // 32,768,000
  u16*   waencT  = (u16*)(ws + 85196800);       // 327,680
  u16*   wdKC    = (u16*)(ws + 85524480);       // 327,680
  u16*   wcat0   = (u16*)(ws + 85852160);       // 4,194,304
  u16*   wcat1   = (u16*)(ws + 90046464);       // 4,194,304
  u16*   wee     = (u16*)(ws + 94240768);       // 2,097,152
  u16*   woutb   = (u16*)(ws + 96337920);       // 5,120,000
  float* bc0     = (float*)(ws + 101457920);    // 8,192
  float* bc1     = (float*)(ws + 101466112);    // 8,192
  u16*   geys    = (u16*)(ws + 101474304);      // 33,816,576 -> ends 135,290,880
  float* att     = (float*)(ws + 135331840);    // 264,192
  u16*   z0b     = (u16*)(ws + 135596032);      // 131,072
  u16*   z1b     = (u16*)(ws + 135727104);      // 131,072
  float* c0      = (float*)(ws + 135858176);    // 131,072
  float* c1      = (float*)(ws + 135989248);    // 131,072
  u16*   zall    = (u16*)(ws + 136120320);      // 8,454,144 -> ends 144,574,464
  // dacc (f32 [2][64][320] = 163,840B) aliases partials (disjoint lifetimes).
  float* dacc    = (float*)(ws + 144574464);    // 163,840
  float* partials= (float*)(ws + 144574464);    // 2,641,920
  float* accum   = (float*)(ws + 147216384);    // 32

  a0_init<<<64,256,0,stream>>>(att, dacc, (float*)z0b, (float*)z1b, c0, c1, accum);
  a1_wcvt<<<512,256,0,stream>>>(waenc, wadec, wih0, whh0, wih1, whh1,
                                bih0, bhh0, bih1, bhh1, wout,
                                waencT, wdKC, wcat0, wcat1, wee, woutb, bc0, bc1);
  a2_encpre<<<800,256,0,stream>>>(hpad, hlen, waencT, hm, encp);
  a3_geys<<<dim3(129,8),256,0,stream>>>(ys, embed, wee, bc0, geys);

  for (int t=0; t<129; t++){
    int p = t & 1, q = p^1;
    k1p<<<2112,256,0,stream>>>(t, encp, hm, hlen, dacc, wcat1, bc1,
                               z0b, z1b, c1, zall, att);
    k2p<<<64,256,0,stream>>>(att + p*64*516, att + q*64*516,
                             z0b + q*64*512, z0b + p*64*512,
                             c0, wcat0, geys + (size_t)t*64*2048,
                             wdKC, dacc + p*20480);
  }
  kf_cell1<<<64,256,0,stream>>>(z0b, z1b + 64*512, z1b, c1, wcat1, bc1,
                                zall + (size_t)128*64*512);

  k4_logits<<<dim3(129,10),512,0,stream>>>(zall, woutb, bout, ys, partials);
  k5_loss<<<33,256,0,stream>>>(partials, ys, accum);
  k6_final<<<1,1,0,stream>>>(accum, (float*)d_out);
}

// Round 17
// 6403.413 us; speedup vs baseline: 1.0311x; 1.0311x over previous
//
#include <hip/hip_runtime.h>
#include <math.h>

typedef unsigned short u16;
typedef float f32x4 __attribute__((ext_vector_type(4)));
typedef short s16x8 __attribute__((ext_vector_type(8)));

#define ODIM 5000
#define NROWS 8256   // 129*64

__device__ inline u16 f2bf(float f){
  unsigned u = __float_as_uint(f);
  return (u16)((u + 0x7FFFu + ((u >> 16) & 1u)) >> 16);
}
__device__ inline float bf2f(u16 h){ return __uint_as_float(((unsigned)h) << 16); }
__device__ inline float sigm(float x){ return 1.f/(1.f + expf(-x)); }

// ---------------- A0: zero state ----------------
__global__ void a0_init(float* att2, float* pd, float* z0f, float* z1f,
                        float* c0, float* c1, float* accum){
  int tid = blockIdx.x*256 + threadIdx.x, n = 64*256;
  for (int i=tid;i<2*64*516;i+=n) att2[i]=0.f;
  for (int i=tid;i<655360;i+=n) pd[i]=0.f;    // pd[64][64][320] u16 = 2.62MB
  for (int i=tid;i<32768;i+=n){ z0f[i]=0.f; z1f[i]=0.f; c0[i]=0.f; c1[i]=0.f; }
  if (tid < 8) accum[tid]=0.f;
}

// ---------------- A1: weight convert / pack ----------------
__global__ void a1_wcvt(const float* waenc, const float* wadec,
  const float* wih0, const float* whh0, const float* wih1, const float* whh1,
  const float* bih0, const float* bhh0, const float* bih1, const float* bhh1,
  const float* wout,
  u16* waencT, u16* wdKC, u16* wcat0, u16* wcat1, u16* wee, u16* woutb,
  float* bc0, float* bc1)
{
  int tid = blockIdx.x*blockDim.x + threadIdx.x;
  int nth = gridDim.x*blockDim.x;
  for (int i=tid; i<320*512; i+=nth){
    int n=i>>9, k=i&511;
    waencT[i] = f2bf(waenc[k*320+n]);
    wdKC[i]   = f2bf(wadec[i]);        // [512][320] row-major direct cast
  }
  for (int i=tid; i<2048*1024; i+=nth){
    int np=i>>10, k=i&1023;
    int u=np>>2, g=np&3, r=g*512+u;
    wcat0[i] = f2bf(k<512 ? wih0[r*1024+512+k] : whh0[r*512+(k-512)]);
    wcat1[i] = f2bf(k<512 ? wih1[r*512+k]      : whh1[r*512+(k-512)]);
  }
  for (int i=tid; i<2048*512; i+=nth){
    int np=i>>9, k=i&511;
    int u=np>>2, g=np&3, r=g*512+u;
    wee[i] = f2bf(wih0[r*1024+k]);
  }
  for (int i=tid; i<5000*512; i+=nth) woutb[i] = f2bf(wout[i]);
  for (int i=tid; i<2048; i+=nth){
    int u=i>>2, g=i&3, r=g*512+u;
    bc0[i] = bih0[r]+bhh0[r];
    bc1[i] = bih1[r]+bhh1[r];
  }
}

// ---------------- A2: hm (masked bf16) + enc_pre = tanh(hm @ Wa_enc) ----------------
__global__ __launch_bounds__(256) void a2_encpre(
  const float* __restrict__ hpad, const int* __restrict__ hlen,
  const u16* __restrict__ waencT, u16* __restrict__ hm, u16* __restrict__ encp)
{
  __shared__ u16 A[64][40];
  __shared__ u16 BT[320][40];
  int tid = threadIdx.x, blk = blockIdx.x;
  int wave = tid>>6, lane = tid&63;
  f32x4 acc[20];
  #pragma unroll
  for (int f=0;f<20;f++) acc[f] = (f32x4){0.f,0.f,0.f,0.f};
  int srow = tid>>2, skoff = (tid&3)*8;
  int grow_s = blk*64 + srow;
  int b_s = grow_s/800, t_s = grow_s - b_s*800;
  bool valid_s = t_s < hlen[b_s];
  for (int c=0;c<16;c++){
    int k0 = c*32;
    {
      const float* src = hpad + (size_t)grow_s*512 + k0 + skoff;
      float4 v0 = *(const float4*)(src);
      float4 v1 = *(const float4*)(src+4);
      if (!valid_s){ v0 = make_float4(0,0,0,0); v1 = make_float4(0,0,0,0); }
      short4 p0 = make_short4((short)f2bf(v0.x),(short)f2bf(v0.y),(short)f2bf(v0.z),(short)f2bf(v0.w));
      short4 p1 = make_short4((short)f2bf(v1.x),(short)f2bf(v1.y),(short)f2bf(v1.z),(short)f2bf(v1.w));
      *(short4*)&A[srow][skoff]   = p0;
      *(short4*)&A[srow][skoff+4] = p1;
      *(short4*)(hm + (size_t)grow_s*512 + k0 + skoff)     = p0;
      *(short4*)(hm + (size_t)grow_s*512 + k0 + skoff + 4) = p1;
    }
    for (int id=tid; id<1280; id+=256){
      int n = id>>2, kv = (id&3)*8;
      *(s16x8*)&BT[n][kv] = *(const s16x8*)(waencT + n*512 + k0 + kv);
    }
    __syncthreads();
    s16x8 av = *(const s16x8*)&A[wave*16 + (lane&15)][(lane>>4)*8];
    #pragma unroll
    for (int f=0;f<20;f++){
      s16x8 bv = *(const s16x8*)&BT[f*16+(lane&15)][(lane>>4)*8];
      acc[f] = __builtin_amdgcn_mfma_f32_16x16x32_bf16(av,bv,acc[f],0,0,0);
    }
    __syncthreads();
  }
  #pragma unroll
  for (int f=0;f<20;f++){
    int col = f*16 + (lane&15);
    #pragma unroll
    for (int r=0;r<4;r++){
      int grow = blk*64 + wave*16 + (lane>>4)*4 + r;
      encp[(size_t)grow*320 + col] = f2bf(tanhf(acc[f][r]));
    }
  }
}

// ---------------- A3: geys = embed[ys_in] @ Wee^T + bc0 ----------------
__global__ __launch_bounds__(256) void a3_geys(
  const int* __restrict__ ys, const float* __restrict__ embed,
  const u16* __restrict__ wee, const float* __restrict__ bc0,
  u16* __restrict__ geys)
{
  __shared__ u16 A[64][88];
  __shared__ u16 BT[256][88];
  int t = blockIdx.x, nt = blockIdx.y, tid = threadIdx.x;
  int wave=tid>>6, lane=tid&63;
  f32x4 acc[16];
  #pragma unroll
  for (int f=0;f<16;f++) acc[f]=(f32x4){0.f,0.f,0.f,0.f};
  int srow = tid>>2, skoff=(tid&3)*16;
  int idx = (t==0) ? (ODIM-1) : ys[srow*128 + (t-1)];
  const float* asrc = embed + (size_t)idx*512;
  for (int c=0;c<8;c++){
    int k0=c*64;
    #pragma unroll
    for (int i=0;i<16;i+=4){
      float4 v = *(const float4*)(asrc + k0 + skoff + i);
      *(short4*)&A[srow][skoff+i] =
        make_short4((short)f2bf(v.x),(short)f2bf(v.y),(short)f2bf(v.z),(short)f2bf(v.w));
    }
    for (int id=tid; id<2048; id+=256){
      int n = id>>3, kv=(id&7)*8;
      *(s16x8*)&BT[n][kv] = *(const s16x8*)(wee + (size_t)(nt*256+n)*512 + k0 + kv);
    }
    __syncthreads();
    #pragma unroll
    for (int kk=0;kk<64;kk+=32){
      s16x8 av = *(const s16x8*)&A[wave*16+(lane&15)][kk+(lane>>4)*8];
      #pragma unroll
      for (int f=0;f<16;f++){
        s16x8 bv = *(const s16x8*)&BT[f*16+(lane&15)][kk+(lane>>4)*8];
        acc[f] = __builtin_amdgcn_mfma_f32_16x16x32_bf16(av,bv,acc[f],0,0,0);
      }
    }
    __syncthreads();
  }
  #pragma unroll
  for (int f=0;f<16;f++){
    int colL = f*16+(lane&15);
    int gc = nt*256+colL;
    float bb = bc0[gc];
    #pragma unroll
    for (int r=0;r<4;r++){
      int row = wave*16 + (lane>>4)*4 + r;
      geys[(size_t)(t*64+row)*2048 + gc] = f2bf(acc[f][r] + bb);
    }
  }
}

// ---------------- K1': att(t) [blocks 0..1023] | cell1(t-1) [blocks 1024..1087] ----------------
// att: 16 chunks x 50 frames per batch (2x wave concurrency vs 512-block version).
// pd combine staged in two 32-slice halves (LDS 22KB -> >=5 blocks/CU).
__global__ __launch_bounds__(256) void k1p(
  int t,
  const u16* __restrict__ encp, const u16* __restrict__ hm, const int* __restrict__ hlen,
  const u16* __restrict__ pd,
  const u16* __restrict__ wcat1, const float* __restrict__ bc1,
  const u16* __restrict__ z0b, u16* __restrict__ z1b, float* __restrict__ c1,
  u16* __restrict__ zall, float* __restrict__ att)
{
  __shared__ __align__(16) char smem[22016];
  const int blk = blockIdx.x, tid = threadIdx.x;
  const int wave = tid>>6, lane = tid&63;
  const int p2 = (t+1)&1;

  if (blk < 1024){
    int b = blk>>4, ch = blk&15;
    float* attp = att + ((t&1)*64*516);
    u16*  pdl  = (u16*)smem;             // [32][320] bf16 = 20480B
    float* dl  = (float*)(smem+20480);   // [320] (disjoint from attl/sl)
    float* attl = (float*)smem;          // [4][512] f32 (after combine)
    float* sl  = (float*)(smem+8192);    // [4]
    // d-combine in two 32-slice halves; per-thread register accumulators
    float dacc[2] = {0.f, 0.f};
    for (int h=0; h<2; h++){
      for (int id=tid; id<1280; id+=256){
        int s = id/40, c8 = (id - s*40)*8;
        *(s16x8*)&pdl[s*320+c8] = *(const s16x8*)(pd + (size_t)(h*32+s)*20480 + b*320 + c8);
      }
      __syncthreads();
      int ci = 0;
      for (int col=tid; col<320; col+=256, ci++){
        float a0=0.f,a1=0.f,a2=0.f,a3=0.f;
        #pragma unroll
        for (int s=0;s<32;s+=4){
          a0 += bf2f(pdl[s*320+col]);
          a1 += bf2f(pdl[(s+1)*320+col]);
          a2 += bf2f(pdl[(s+2)*320+col]);
          a3 += bf2f(pdl[(s+3)*320+col]);
        }
        dacc[ci] += (a0+a1)+(a2+a3);
      }
      __syncthreads();
    }
    {
      int ci = 0;
      for (int col=tid; col<320; col+=256, ci++) dl[col] = tanhf(dacc[ci]);
    }
    __syncthreads();
    float dreg[8];
    #pragma unroll
    for (int j=0;j<8;j++) dreg[j] = (lane<40) ? dl[lane*8+j] : 0.f;
    float attacc[8];
    #pragma unroll
    for (int j=0;j<8;j++) attacc[j]=0.f;
    float sacc = 0.f;
    int len = hlen[b];
    int t0 = ch*50;
    int tend = t0+50 < len ? t0+50 : len;
    for (int i0 = t0 + wave; i0 < tend; i0 += 16){
      s16x8 ev[4], hv[4];
      #pragma unroll
      for (int q=0;q<4;q++){
        int tt = i0 + 4*q;
        if (tt < tend){
          if (lane<40) ev[q] = *(const s16x8*)(encp + (size_t)(b*800+tt)*320 + lane*8);
          hv[q] = *(const s16x8*)(hm + (size_t)(b*800+tt)*512 + lane*8);
        }
      }
      #pragma unroll
      for (int q=0;q<4;q++){
        int tt = i0 + 4*q;
        if (tt < tend){
          float e = 0.f;
          if (lane<40){
            #pragma unroll
            for (int j=0;j<8;j++) e += dreg[j]*bf2f((u16)ev[q][j]);
          }
          #pragma unroll
          for (int off=32; off; off>>=1) e += __shfl_xor(e, off);
          float pw = expf(fminf(e, 60.f));
          sacc += pw;
          #pragma unroll
          for (int j=0;j<8;j++) attacc[j] += pw*bf2f((u16)hv[q][j]);
        }
      }
    }
    __syncthreads();
    #pragma unroll
    for (int j=0;j<8;j++) attl[wave*512 + lane*8+j] = attacc[j];
    if (lane==0) sl[wave] = sacc;
    __syncthreads();
    for (int c2 = tid; c2 < 512; c2 += 256){
      float v = attl[c2]+attl[512+c2]+attl[1024+c2]+attl[1536+c2];
      atomicAdd(&attp[b*516 + c2], v);
    }
    if (tid==0) atomicAdd(&attp[b*516 + 512], sl[0]+sl[1]+sl[2]+sl[3]);
  } else {
    // cell1 for step t-1
    if (t < 1) return;
    int nb = blk - 1024;
    const u16* z0n = z0b + p2*64*512;          // z0 of step t-1 (parity (t-1)&1 = p2)
    const u16* z1p = z1b + ((p2^1)*64*512);
    u16* z1n = z1b + p2*64*512;
    u16* zallt = zall + (size_t)(t-1)*64*512;
    u16 (*A)[88]  = (u16(*)[88])smem;
    u16 (*BT)[88] = (u16(*)[88])(smem+11264);
    f32x4 acc[2];
    acc[0]=(f32x4){0.f,0.f,0.f,0.f}; acc[1]=(f32x4){0.f,0.f,0.f,0.f};
    int srow=tid>>2, skoff=(tid&3)*16;
    int brow=tid>>3, bkoff=(tid&7)*8;
    for (int c=0;c<16;c++){
      int k0=c*64;
      const u16* asrc = (c<8) ? (z0n + srow*512 + k0 + skoff)
                              : (z1p + srow*512 + (k0-512) + skoff);
      *(s16x8*)&A[srow][skoff]   = *(const s16x8*)asrc;
      *(s16x8*)&A[srow][skoff+8] = *(const s16x8*)(asrc+8);
      *(s16x8*)&BT[brow][bkoff] = *(const s16x8*)(wcat1 + (size_t)(nb*32+brow)*1024 + k0 + bkoff);
      __syncthreads();
      #pragma unroll
      for (int kk=0;kk<64;kk+=32){
        s16x8 av = *(const s16x8*)&A[wave*16+(lane&15)][kk+(lane>>4)*8];
        #pragma unroll
        for (int f=0;f<2;f++){
          s16x8 bv = *(const s16x8*)&BT[f*16+(lane&15)][kk+(lane>>4)*8];
          acc[f] = __builtin_amdgcn_mfma_f32_16x16x32_bf16(av,bv,acc[f],0,0,0);
        }
      }
      __syncthreads();
    }
    float (*gl)[36] = (float(*)[36])smem;
    #pragma unroll
    for (int f=0;f<2;f++){
      int colL = f*16+(lane&15);
      float bb = bc1[nb*32+colL];
      #pragma unroll
      for (int r=0;r<4;r++){
        int rowL = wave*16+(lane>>4)*4+r;
        gl[rowL][colL] = acc[f][r] + bb;
      }
    }
    __syncthreads();
    for (int it=tid; it<512; it+=256){
      int bb=it>>3, ul=it&7;
      float gi=gl[bb][ul*4], gf=gl[bb][ul*4+1], gg=gl[bb][ul*4+2], go=gl[bb][ul*4+3];
      int ug = nb*8+ul;
      float cp = c1[bb*512+ug];
      float cn = sigm(gf)*cp + sigm(gi)*tanhf(gg);
      float z = sigm(go)*tanhf(cn);
      c1[bb*512+ug]=cn;
      u16 zb = f2bf(z);
      z1n[bb*512+ug]=zb;
      zallt[bb*512+ug]=zb;
    }
  }
}

// ---------------- K2': cell0(t) (64 blocks) + bf16 pd-partials + att-zero ----------------
__global__ __launch_bounds__(256) void k2p(
  const float* __restrict__ attp, float* __restrict__ attz,
  const u16* __restrict__ z0p, u16* __restrict__ z0n,
  float* __restrict__ c0,
  const u16* __restrict__ wcat0, const u16* __restrict__ geyt,
  const u16* __restrict__ wdKC, u16* __restrict__ pdout)
{
  __shared__ __align__(16) char smem[16896];
  __shared__ float sinv[64];
  __shared__ float zsl[512];     // z[b=64][ul=8] for this block's u-slice
  __shared__ u16 wsl[2560];      // wdKC rows nb*8..nb*8+8 (8x320)
  u16 (*A)[88]  = (u16(*)[88])smem;
  u16 (*BT)[88] = (u16(*)[88])(smem+11264);
  int tid = threadIdx.x, nb = blockIdx.x;
  int wave=tid>>6, lane=tid&63;
  if (tid < 64) sinv[tid] = 1.f/attp[tid*516+512];
  for (int id=tid; id<320; id+=256)
    *(s16x8*)&wsl[id*8] = *(const s16x8*)(wdKC + (size_t)nb*2560 + id*8);
  __syncthreads();
  f32x4 acc[2];
  acc[0]=(f32x4){0.f,0.f,0.f,0.f}; acc[1]=(f32x4){0.f,0.f,0.f,0.f};
  int srow=tid>>2, skoff=(tid&3)*16;
  int brow=tid>>3, bkoff=(tid&7)*8;
  for (int c=0;c<16;c++){
    int k0=c*64;
    if (c<8){
      const float* src = attp + srow*516 + k0 + skoff;
      float sv = sinv[srow];
      #pragma unroll
      for (int i=0;i<16;i+=4){
        float4 v = *(const float4*)(src+i);
        *(short4*)&A[srow][skoff+i] = make_short4(
          (short)f2bf(v.x*sv),(short)f2bf(v.y*sv),(short)f2bf(v.z*sv),(short)f2bf(v.w*sv));
      }
    } else {
      const u16* src = z0p + srow*512 + (k0-512) + skoff;
      *(s16x8*)&A[srow][skoff]   = *(const s16x8*)(src);
      *(s16x8*)&A[srow][skoff+8] = *(const s16x8*)(src+8);
    }
    *(s16x8*)&BT[brow][bkoff] = *(const s16x8*)(wcat0 + (size_t)(nb*32+brow)*1024 + k0 + bkoff);
    __syncthreads();
    #pragma unroll
    for (int kk=0;kk<64;kk+=32){
      s16x8 av = *(const s16x8*)&A[wave*16+(lane&15)][kk+(lane>>4)*8];
      #pragma unroll
      for (int f=0;f<2;f++){
        s16x8 bv = *(const s16x8*)&BT[f*16+(lane&15)][kk+(lane>>4)*8];
        acc[f] = __builtin_amdgcn_mfma_f32_16x16x32_bf16(av,bv,acc[f],0,0,0);
      }
    }
    __syncthreads();
  }
  float (*gl)[36] = (float(*)[36])smem;
  #pragma unroll
  for (int f=0;f<2;f++){
    int colL = f*16+(lane&15);
    #pragma unroll
    for (int r=0;r<4;r++){
      int rowL = wave*16+(lane>>4)*4+r;
      gl[rowL][colL] = acc[f][r] + bf2f(geyt[rowL*2048 + nb*32 + colL]);
    }
  }
  __syncthreads();
  for (int it=tid; it<512; it+=256){
    int bb=it>>3, ul=it&7;
    float gi=gl[bb][ul*4], gf=gl[bb][ul*4+1], gg=gl[bb][ul*4+2], go=gl[bb][ul*4+3];
    int ug = nb*8+ul;
    float cp = c0[bb*512+ug];
    float cn = sigm(gf)*cp + sigm(gi)*tanhf(gg);
    float z = sigm(go)*tanhf(cn);
    c0[bb*512+ug]=cn;
    z0n[bb*512+ug]=f2bf(z);
    zsl[it] = z;
  }
  __syncthreads();
  // pd partial (bf16): pdout[nb*20480 + b*320 + col] = sum_ul z[b][ul]*W[nb*8+ul][col]
  for (int idx=tid; idx<20480; idx+=256){
    int b = idx/320, col = idx - b*320;
    float a = 0.f;
    #pragma unroll
    for (int ul=0; ul<8; ul++)
      a += zsl[b*8+ul]*bf2f(wsl[ul*320+col]);
    pdout[(size_t)nb*20480 + idx] = f2bf(a);
  }
  for (int i=tid + nb*256; i < 64*516; i += 64*256) attz[i] = 0.f;
}

// ---------------- KF: final cell1(128) (64 blocks) ----------------
__global__ __launch_bounds__(256) void kf_cell1(
  const u16* __restrict__ z0n, const u16* __restrict__ z1p,
  u16* __restrict__ z1n, float* __restrict__ c1,
  const u16* __restrict__ wcat1, const float* __restrict__ bc1,
  u16* __restrict__ zallt)
{
  __shared__ __align__(16) char smem[25600];
  int tid = threadIdx.x, wave=tid>>6, lane=tid&63;
  int nb = blockIdx.x;
  u16 (*A)[88]  = (u16(*)[88])smem;
  u16 (*BT)[88] = (u16(*)[88])(smem+11264);
  f32x4 acc[2];
  acc[0]=(f32x4){0.f,0.f,0.f,0.f}; acc[1]=(f32x4){0.f,0.f,0.f,0.f};
  int srow=tid>>2, skoff=(tid&3)*16;
  int brow=tid>>3, bkoff=(tid&7)*8;
  for (int c=0;c<16;c++){
    int k0=c*64;
    const u16* asrc = (c<8) ? (z0n + srow*512 + k0 + skoff)
                            : (z1p + srow*512 + (k0-512) + skoff);
    *(s16x8*)&A[srow][skoff]   = *(const s16x8*)asrc;
    *(s16x8*)&A[srow][skoff+8] = *(const s16x8*)(asrc+8);
    *(s16x8*)&BT[brow][bkoff] = *(const s16x8*)(wcat1 + (size_t)(nb*32+brow)*1024 + k0 + bkoff);
    __syncthreads();
    #pragma unroll
    for (int kk=0;kk<64;kk+=32){
      s16x8 av = *(const s16x8*)&A[wave*16+(lane&15)][kk+(lane>>4)*8];
      #pragma unroll
      for (int f=0;f<2;f++){
        s16x8 bv = *(const s16x8*)&BT[f*16+(lane&15)][kk+(lane>>4)*8];
        acc[f] = __builtin_amdgcn_mfma_f32_16x16x32_bf16(av,bv,acc[f],0,0,0);
      }
    }
    __syncthreads();
  }
  float (*gl)[36] = (float(*)[36])smem;
  #pragma unroll
  for (int f=0;f<2;f++){
    int colL = f*16+(lane&15);
    float bb = bc1[nb*32+colL];
    #pragma unroll
    for (int r=0;r<4;r++){
      int rowL = wave*16+(lane>>4)*4+r;
      gl[rowL][colL] = acc[f][r] + bb;
    }
  }
  __syncthreads();
  for (int it=tid; it<512; it+=256){
    int bb=it>>3, ul=it&7;
    float gi=gl[bb][ul*4], gf=gl[bb][ul*4+1], gg=gl[bb][ul*4+2], go=gl[bb][ul*4+3];
    int ug = nb*8+ul;
    float cp = c1[bb*512+ug];
    float cn = sigm(gf)*cp + sigm(gi)*tanhf(gg);
    float z = sigm(go)*tanhf(cn);
    c1[bb*512+ug]=cn;
    u16 zb = f2bf(z);
    z1n[bb*512+ug]=zb;
    zallt[bb*512+ug]=zb;
  }
}

// ---------------- K4: logits GEMM + per-(row,vtile) softmax partials ----------------
__global__ __launch_bounds__(512) void k4_logits(
  const u16* __restrict__ zall, const u16* __restrict__ woutb,
  const float* __restrict__ b_out, const int* __restrict__ ys,
  float* __restrict__ partials)
{
  __shared__ char smem[46080];
  u16 (*A)[40]  = (u16(*)[40])smem;
  u16 (*BT)[40] = (u16(*)[40])(smem + 5120);
  int t = blockIdx.x, v = blockIdx.y;
  int tid = threadIdx.x, wave = tid>>6, lane = tid&63;
  int mf = wave>>1;
  int nh = (wave&1)*256;
  f32x4 acc[16];
  #pragma unroll
  for (int f=0;f<16;f++) acc[f]=(f32x4){0.f,0.f,0.f,0.f};
  for (int c=0;c<16;c++){
    int k0 = c*32;
    { int row = tid>>3, koff=(tid&7)*4;
      *(short4*)&A[row][koff] = *(const short4*)(zall + (size_t)(t*64+row)*512 + k0 + koff); }
    { int n = v*512 + tid;
      if (n < ODIM){
        const u16* src = woutb + (size_t)n*512 + k0;
        #pragma unroll
        for (int i=0;i<32;i+=8) *(s16x8*)&BT[tid][i] = *(const s16x8*)(src+i);
      } else {
        s16x8 z = 0;
        #pragma unroll
        for (int i=0;i<32;i+=8) *(s16x8*)&BT[tid][i] = z;
      }
    }
    __syncthreads();
    s16x8 av = *(const s16x8*)&A[mf*16 + (lane&15)][(lane>>4)*8];
    #pragma unroll
    for (int f=0;f<16;f++){
      s16x8 bv = *(const s16x8*)&BT[nh + f*16 + (lane&15)][(lane>>4)*8];
      acc[f] = __builtin_amdgcn_mfma_f32_16x16x32_bf16(av,bv,acc[f],0,0,0);
    }
    __syncthreads();
  }
  float (*ll)[518] = (float(*)[518])smem;
  for (int g=0; g<4; g++){
    if (mf == g){
      #pragma unroll
      for (int f=0;f<16;f++){
        int colL = nh + f*16 + (lane&15);
        int gcol = v*512 + colL;
        float bo = (gcol < ODIM) ? b_out[gcol] : 0.f;
        #pragma unroll
        for (int r=0;r<4;r++){
          int rowL = (lane>>4)*4 + r;
          ll[rowL][colL] = acc[f][r] + bo;
        }
      }
    }
    __syncthreads();
    int r = tid>>5, j = tid&31;
    float m = -1e30f, s = 0.f, amax = -1e30f; int aidx = 0;
    #pragma unroll
    for (int i=0;i<16;i++){
      int cL = j + 32*i;
      int gc = v*512 + cL;
      if (gc < ODIM){
        float val = ll[r][cL];
        if (val > m){ s = s*expf(m-val) + 1.f; m = val; }
        else s += expf(val - m);
        if (val > amax){ amax = val; aidx = gc; }
      }
    }
    #pragma unroll
    for (int off=16; off; off>>=1){
      float mo = __shfl_xor(m, off), so = __shfl_xor(s, off);
      float ao = __shfl_xor(amax, off); int io = __shfl_xor(aidx, off);
      float M = fmaxf(m, mo);
      s = s*expf(m-M) + so*expf(mo-M);
      m = M;
      if (ao > amax || (ao == amax && io < aidx)){ amax = ao; aidx = io; }
    }
    if (j == 0){
      int b = g*16 + r;
      int grow = t*64 + b;
      int lab = (t < 128) ? ys[b*128 + t] : (ODIM-1);
      float labval = 0.f, labf = 0.f;
      int lo = lab - v*512;
      if (lo >= 0 && lo < 512){ labval = ll[r][lo]; labf = 1.f; }
      float* pp = partials + (size_t)(grow*10 + v)*8;
      pp[0]=m; pp[1]=s; pp[2]=amax; pp[3]=__int_as_float(aidx); pp[4]=labval; pp[5]=labf;
    }
    __syncthreads();
  }
}

// ---------------- K5: combine partials -> nll/correct -> atomics ----------------
__global__ __launch_bounds__(256) void k5_loss(
  const float* __restrict__ partials, const int* __restrict__ ys, float* accum)
{
  int row = blockIdx.x*256 + threadIdx.x;
  float nll = 0.f; int corr = 0;
  if (row < NROWS){
    float M=-1e30f, S=0.f, amax=-1e30f, labval=0.f; int aidx=0;
    for (int v=0;v<10;v++){
      const float* pp = partials + (size_t)(row*10+v)*8;
      float m=pp[0], s=pp[1], a=pp[2]; int ai=__float_as_int(pp[3]);
      float MM = fmaxf(M, m);
      S = S*expf(M-MM) + s*expf(m-MM);
      M = MM;
      if (a > amax || (a == amax && ai < aidx)){ amax=a; aidx=ai; }
      if (pp[5] != 0.f) labval = pp[4];
    }
    nll = M + logf(S) - labval;
    int t = row>>6, b = row&63;
    int lab = (t < 128) ? ys[b*128+t] : (ODIM-1);
    corr = (aidx == lab) ? 1 : 0;
  }
  __shared__ float sn[256]; __shared__ int sc[256];
  sn[threadIdx.x]=nll; sc[threadIdx.x]=corr; __syncthreads();
  for (int st=128; st; st>>=1){
    if (threadIdx.x<st){ sn[threadIdx.x]+=sn[threadIdx.x+st]; sc[threadIdx.x]+=sc[threadIdx.x+st]; }
    __syncthreads();
  }
  if (threadIdx.x==0){
    atomicAdd(accum, sn[0]);
    atomicAdd((int*)accum + 1, sc[0]);
  }
}

__global__ void k6_final(const float* accum, float* out){
  out[0] = accum[0]/(float)NROWS * 128.f;
  out[1] = (float)(((const int*)accum)[1])/(float)NROWS;
}

// ---------------- launch ----------------
extern "C" void kernel_launch(void* const* d_in, const int* in_sizes, int n_in,
                              void* d_out, int out_size, void* d_ws, size_t ws_size,
                              hipStream_t stream)
{
  const float* hpad  = (const float*)d_in[0];
  const int*   hlen  = (const int*)d_in[1];
  const int*   ys    = (const int*)d_in[2];
  const float* embed = (const float*)d_in[3];
  const float* wih0  = (const float*)d_in[4];
  const float* whh0  = (const float*)d_in[5];
  const float* bih0  = (const float*)d_in[6];
  const float* bhh0  = (const float*)d_in[7];
  const float* wih1  = (const float*)d_in[8];
  const float* whh1  = (const float*)d_in[9];
  const float* bih1  = (const float*)d_in[10];
  const float* bhh1  = (const float*)d_in[11];
  const float* waenc = (const float*)d_in[12];
  const float* wadec = (const float*)d_in[13];
  const float* wout  = (const float*)d_in[14];
  const float* bout  = (const float*)d_in[15];

  char* ws = (char*)d_ws;
  u16*   hm      = (u16*)(ws + 0);              // 52,428,800
  u16*   encp    = (u16*)(ws + 52428800);       // 32,768,000
  u16*   waencT  = (u16*)(ws + 85196800);       // 327,680
  u16*   wdKC    = (u16*)(ws + 85524480);       // 327,680
  u16*   wcat0   = (u16*)(ws + 85852160);       // 4,194,304
  u16*   wcat1   = (u16*)(ws + 90046464);       // 4,194,304
  u16*   wee     = (u16*)(ws + 94240768);       // 2,097,152
  u16*   woutb   = (u16*)(ws + 96337920);       // 5,120,000
  float* bc0     = (float*)(ws + 101457920);    // 8,192
  float* bc1     = (float*)(ws + 101466112);    // 8,192
  u16*   geys    = (u16*)(ws + 101474304);      // 33,816,576 -> ends 135,290,880
  float* att     = (float*)(ws + 135331840);    // 264,192
  u16*   z0b     = (u16*)(ws + 135596032);      // 131,072
  u16*   z1b     = (u16*)(ws + 135727104);      // 131,072
  float* c0      = (float*)(ws + 135858176);    // 131,072
  float* c1      = (float*)(ws + 135989248);    // 131,072
  u16*   zall    = (u16*)(ws + 136120320);      // 8,454,144 -> ends 144,574,464
  // pd (bf16 [64][64][320] = 2,621,440B) aliases partials (disjoint lifetimes).
  u16*   pd      = (u16*)(ws + 144574464);      // 2,621,440
  float* partials= (float*)(ws + 144574464);    // 2,641,920
  float* accum   = (float*)(ws + 147216384);    // 32

  a0_init<<<64,256,0,stream>>>(att, (float*)pd, (float*)z0b, (float*)z1b, c0, c1, accum);
  a1_wcvt<<<512,256,0,stream>>>(waenc, wadec, wih0, whh0, wih1, whh1,
                                bih0, bhh0, bih1, bhh1, wout,
                                waencT, wdKC, wcat0, wcat1, wee, woutb, bc0, bc1);
  a2_encpre<<<800,256,0,stream>>>(hpad, hlen, waencT, hm, encp);
  a3_geys<<<dim3(129,8),256,0,stream>>>(ys, embed, wee, bc0, geys);

  for (int t=0; t<129; t++){
    int p = t & 1, q = p^1;
    k1p<<<1088,256,0,stream>>>(t, encp, hm, hlen, pd, wcat1, bc1,
                               z0b, z1b, c1, zall, att);
    k2p<<<64,256,0,stream>>>(att + p*64*516, att + q*64*516,
                             z0b + q*64*512, z0b + p*64*512,
                             c0, wcat0, geys + (size_t)t*64*2048,
                             wdKC, pd);
  }
  kf_cell1<<<64,256,0,stream>>>(z0b, z1b + 64*512, z1b, c1, wcat1, bc1,
                                zall + (size_t)128*64*512);

  k4_logits<<<dim3(129,10),512,0,stream>>>(zall, woutb, bout, ys, partials);
  k5_loss<<<33,256,0,stream>>>(partials, ys, accum);
  k6_final<<<1,1,0,stream>>>(accum, (float*)d_out);
}